// Round 4
// baseline (400.411 us; speedup 1.0000x reference)
//
#include <hip/hip_runtime.h>
#include <stdint.h>

#define NPTS 4096
#define NW   64            // 64-bit words per adjacency row
#define SENT NPTS
#define MAXSP 512
#define ROWS 8             // rows per wave in k_adj
#define ECAP 131072        // edge capacity per batch (~10x margin)

// ---------------- K0: pack coords into float4(x,y,z,sq); zero edge counters -
__global__ void k_prep(const float* __restrict__ coords,
                       float4* __restrict__ pts,
                       int* __restrict__ ecnt, int batches){
#pragma clang fp contract(off)
  int g = blockIdx.x * blockDim.x + threadIdx.x;   // 8*4096
  if (blockIdx.x == 0 && threadIdx.x < batches) ecnt[threadIdx.x] = 0;
  float x = coords[g*3+0], y = coords[g*3+1], z = coords[g*3+2];
  // sq: round each square, then sequential adds (XLA mul + reduce, no FMA)
  float sq = ((x*x) + (y*y)) + (z*z);
  pts[g] = make_float4(x, y, z, sq);
}

// ---------------- K1: adjacency bitset + degree/core ------------------------
// one wave handles ROWS=8 rows; word k built with __ballot (j = k*64+lane)
__global__ void k_adj(const float4* __restrict__ pts,
                      unsigned long long* __restrict__ adj,
                      int* __restrict__ core){
#pragma clang fp contract(off)
  int wv   = (blockIdx.x * blockDim.x + threadIdx.x) >> 6;   // 4096 waves
  int lane = threadIdx.x & 63;
  int b  = wv >> 9;                 // 512 waves per batch
  int i0 = (wv & 511) << 3;         // first of 8 rows
  const float4* pb = pts + (b << 12);
  float4 pi[ROWS];
  #pragma unroll
  for (int r = 0; r < ROWS; ++r) pi[r] = pb[i0 + r];
  const float EPS2 = (float)(0.06 * 0.06);
  unsigned long long w[ROWS];
  int deg[ROWS];
  #pragma unroll
  for (int r = 0; r < ROWS; ++r){ w[r] = 0ULL; deg[r] = 0; }
  #pragma unroll 2
  for (int k = 0; k < 64; ++k){
    float4 pj = pb[(k << 6) + lane];
    #pragma unroll
    for (int r = 0; r < ROWS; ++r){
      // dot: ascending-k FMA chain, first product plainly rounded (XLA gebp)
      float dot = __builtin_fmaf(pi[r].z, pj.z,
                  __builtin_fmaf(pi[r].y, pj.y, pi[r].x * pj.x));
      // rn(s - rn(2*dot)) == fma(-2,dot,s) since 2*dot is exact
      float d2 = __builtin_fmaf(-2.0f, dot, pi[r].w + pj.w);
      unsigned long long bal = __ballot(d2 <= EPS2);
      if (lane == k) w[r] = bal;
      deg[r] += __popcll(bal);
    }
  }
  size_t rowg = ((size_t)b << 12) + i0;
  #pragma unroll
  for (int r = 0; r < ROWS; ++r) adj[(rowg + r) * NW + lane] = w[r];
  if (lane == 0){
    #pragma unroll
    for (int r = 0; r < ROWS; ++r) core[rowg + r] = (deg[r] >= 3) ? 1 : 0;
  }
}

// ---------------- K2: core bitset (one wave per batch) ----------------------
__global__ void k_corebits(const int* __restrict__ core,
                           unsigned long long* __restrict__ corebits){
  int b = blockIdx.x;
  int lane = threadIdx.x;   // 64 threads
  unsigned long long myword = 0ULL;
  for (int k = 0; k < 64; ++k){
    unsigned long long bal = __ballot(core[(b << 12) + (k << 6) + lane] != 0);
    if (lane == k) myword = bal;
  }
  corebits[(b << 6) + lane] = myword;
}

// ---------------- K3: extract core-core edges (j > i), packed i<<12|j -------
__global__ void k_edges(const unsigned long long* __restrict__ adj,
                        const unsigned long long* __restrict__ corebits,
                        const int* __restrict__ core,
                        uint32_t* __restrict__ edges, int* __restrict__ ecnt){
  int wv   = (blockIdx.x * blockDim.x + threadIdx.x) >> 6;   // global row
  int lane = threadIdx.x & 63;
  int b = wv >> 12;
  int i = wv & (NPTS - 1);
  if (!core[wv]) return;                       // wave-uniform exit
  unsigned long long m = adj[(size_t)wv * NW + lane] & corebits[(b << 6) + lane];
  int base = lane << 6;
  if (base + 63 <= i) m = 0ULL;                       // whole word j <= i
  else if (base <= i) m &= (~0ULL) << (i - base + 1); // keep j > i
  int cnt = __popcll(m);
  // wave inclusive scan of cnt
  int incl = cnt;
  #pragma unroll
  for (int off = 1; off < 64; off <<= 1){
    int y = __shfl_up(incl, off);
    if (lane >= off) incl += y;
  }
  int total = __shfl(incl, 63);
  if (total == 0) return;
  int wbase = 0;
  if (lane == 63) wbase = atomicAdd(&ecnt[b], total);
  wbase = __shfl(wbase, 63);
  int pos = wbase + incl - cnt;
  uint32_t* eb = edges + (size_t)b * ECAP;
  while (m){
    int bit = __builtin_ctzll(m);
    m &= m - 1;
    int p = min(pos, ECAP - 1);
    eb[p] = ((uint32_t)i << 12) | (uint32_t)(base + bit);
    pos++;
  }
}

// ---------------- K4: per-batch connected components in LDS -----------------
// lab[i] -> min index of i's core-component (for core i); deterministic
// fixed point (atomicMin is commutative; exit only after a clean full sweep).
__global__ __launch_bounds__(1024) void k_cc(const uint32_t* __restrict__ edges,
                                             const int* __restrict__ ecnt,
                                             int* __restrict__ lab_g){
  __shared__ int lab[NPTS];
  __shared__ int chg;
  int b = blockIdx.x, t = threadIdx.x;
  for (int s = 0; s < 4; ++s){ int v = (t << 2) + s; lab[v] = v; }
  __syncthreads();
  int cnt = min(ecnt[b], ECAP);
  const uint32_t* eb = edges + (size_t)b * ECAP;
  while (true){
    if (t == 0) chg = 0;
    __syncthreads();
    for (int e = t; e < cnt; e += 1024){
      uint32_t pk = eb[e];
      int u = pk >> 12, v = pk & 4095;
      int a = lab[u], c = lab[v];
      if (a < c)      { if (atomicMin(&lab[v], a) > a) chg = 1; }
      else if (c < a) { if (atomicMin(&lab[u], c) > c) chg = 1; }
    }
    __syncthreads();
    if (!chg) break;     // clean sweep: no lowering anywhere -> all edges equal
    // pointer jumping x3 (own-slot writes; racy reads are monotone-safe)
    for (int s = 0; s < 4; ++s){
      int v = (t << 2) + s;
      int l = lab[v];
      l = min(l, lab[l]); l = min(l, lab[l]); l = min(l, lab[l]);
      lab[v] = l;
    }
    __syncthreads();
  }
  for (int s = 0; s < 4; ++s){ int v = (t << 2) + s; lab_g[(b << 12) + v] = lab[v]; }
}

// ---------------- K5: labels (core: lab[i]; border: min core-neighbor lab) --
__global__ void k_labels(const unsigned long long* __restrict__ adj,
                         const unsigned long long* __restrict__ corebits,
                         const int* __restrict__ core,
                         const int* __restrict__ lab_g,
                         int* __restrict__ labels){
  int wv   = (blockIdx.x * blockDim.x + threadIdx.x) >> 6;
  int lane = threadIdx.x & 63;
  int b = wv >> 12;
  int i = wv & (NPTS - 1);
  const int* lb = lab_g + (b << 12);
  unsigned long long m = adj[(size_t)wv * NW + lane] & corebits[(b << 6) + lane];
  int mn = SENT;
  int base = lane << 6;
  while (m){
    int bit = __builtin_ctzll(m);
    m &= m - 1;
    mn = min(mn, lb[base + bit]);
  }
  #pragma unroll
  for (int off = 32; off; off >>= 1) mn = min(mn, __shfl_xor(mn, off));
  if (lane == 0){
    labels[wv] = core[wv] ? lb[i] : mn;   // SENT if no core neighbor
  }
}

// ---------------- K6: per-batch finalize (noise fill, compact, cap) ---------
__global__ __launch_bounds__(1024) void k_final(const int* __restrict__ labels_g,
                                                int* __restrict__ out){
  __shared__ int LAB[NPTS];
  __shared__ int A[NPTS];
  __shared__ int B[NPTS];
  __shared__ int scanbuf[1024];
  __shared__ int sMost;
  int b = blockIdx.x;
  int t = threadIdx.x;
  const int* lg = labels_g + (b << 12);

  for (int s = 0; s < 4; ++s){ int v = (t << 2) + s; LAB[v] = lg[v]; A[v] = 0; }
  if (t == 0) sMost = -1;
  __syncthreads();
  for (int s = 0; s < 4; ++s){ int l = LAB[(t << 2) + s]; if (l < SENT) atomicAdd(&A[l], 1); }
  __syncthreads();
  for (int s = 0; s < 4; ++s){
    int v = (t << 2) + s; int c = A[v];
    if (c > 0) atomicMax(&sMost, (c << 13) | (4095 - v));
  }
  __syncthreads();
  int most = (sMost >= 0) ? (4095 - (sMost & 8191)) : 0;
  for (int s = 0; s < 4; ++s){ int v = (t << 2) + s; if (LAB[v] == SENT) LAB[v] = most; B[v] = 0; }
  __syncthreads();
  for (int s = 0; s < 4; ++s) B[LAB[(t << 2) + s]] = 1;
  __syncthreads();
  int pv[4]; int ls = 0;
  for (int s = 0; s < 4; ++s){ pv[s] = B[(t << 2) + s]; ls += pv[s]; }
  scanbuf[t] = ls;
  __syncthreads();
  for (int off = 1; off < 1024; off <<= 1){
    int x = scanbuf[t];
    int y = (t >= off) ? scanbuf[t - off] : 0;
    __syncthreads();
    scanbuf[t] = x + y;
    __syncthreads();
  }
  int ncl = scanbuf[1023];
  int run = (t > 0) ? scanbuf[t - 1] : 0;
  for (int s = 0; s < 4; ++s){ run += pv[s]; B[(t << 2) + s] = run - 1; }
  __syncthreads();
  for (int s = 0; s < 4; ++s){ int v = (t << 2) + s; LAB[v] = B[LAB[v]]; }
  __syncthreads();
  if (ncl > MAXSP){
    for (int s = 0; s < 4; ++s) A[(t << 2) + s] = 0;
    __syncthreads();
    for (int s = 0; s < 4; ++s) atomicAdd(&A[LAB[(t << 2) + s]], 1);
    __syncthreads();
    for (int s = 0; s < 4; ++s){
      int v = (t << 2) + s;
      int keyv = A[v] * NPTS + v;
      int pos = 0;
      for (int u = 0; u < NPTS; ++u) pos += ((A[u] * NPTS + u) < keyv) ? 1 : 0;
      B[v] = (pos >= NPTS - MAXSP) ? (pos - (NPTS - MAXSP)) : 0;
    }
    __syncthreads();
    for (int s = 0; s < 4; ++s){ int v = (t << 2) + s; LAB[v] = B[LAB[v]]; }
    __syncthreads();
  }
  int* og = out + (b << 12);
  for (int s = 0; s < 4; ++s){ int v = (t << 2) + s; og[v] = LAB[v]; }
}

// ---------------- launch ----------------------------------------------------
extern "C" void kernel_launch(void* const* d_in, const int* in_sizes, int n_in,
                              void* d_out, int out_size, void* d_ws, size_t ws_size,
                              hipStream_t stream){
  const float* coords = (const float*)d_in[0];
  int* out = (int*)d_out;
  int batches = in_sizes[0] / (NPTS * 3);   // 8

  char* ws = (char*)d_ws;
  unsigned long long* adj = (unsigned long long*)ws;                  // 16 MB
  size_t off = (size_t)batches * NPTS * NW * sizeof(unsigned long long);
  int* core   = (int*)(ws + off); off += (size_t)batches * NPTS * sizeof(int);
  unsigned long long* corebits = (unsigned long long*)(ws + off);
  off += (size_t)batches * 64 * sizeof(unsigned long long);
  int* lab_g  = (int*)(ws + off); off += (size_t)batches * NPTS * sizeof(int);
  int* labels = (int*)(ws + off); off += (size_t)batches * NPTS * sizeof(int);
  float4* pts = (float4*)(ws + off); off += (size_t)batches * NPTS * sizeof(float4);
  int* ecnt   = (int*)(ws + off); off += (size_t)batches * sizeof(int);
  off = (off + 255) & ~(size_t)255;
  uint32_t* edges = (uint32_t*)(ws + off); off += (size_t)batches * ECAP * sizeof(uint32_t);

  int npts_all = batches * NPTS;
  // K0: pack float4(x,y,z,sq) + zero edge counters
  k_prep<<<npts_all / 256, 256, 0, stream>>>(coords, pts, ecnt, batches);
  // K1: adjacency, 8 rows per wave
  k_adj<<<npts_all / (ROWS * 4), 256, 0, stream>>>(pts, adj, core);
  // K2: core bitset
  k_corebits<<<batches, 64, 0, stream>>>(core, corebits);
  // K3: edge extraction
  k_edges<<<npts_all / 4, 256, 0, stream>>>(adj, corebits, core, edges, ecnt);
  // K4: per-batch CC in LDS
  k_cc<<<batches, 1024, 0, stream>>>(edges, ecnt, lab_g);
  // K5: label extraction
  k_labels<<<npts_all / 4, 256, 0, stream>>>(adj, corebits, core, lab_g, labels);
  // K6: per-batch finalize
  k_final<<<batches, 1024, 0, stream>>>(labels, out);
}

// Round 5
// 175.136 us; speedup vs baseline: 2.2863x; 2.2863x over previous
//
#include <hip/hip_runtime.h>
#include <stdint.h>

#define NPTS 4096
#define NW   64            // 64-bit words per adjacency row
#define SENT NPTS
#define MAXSP 512
#define ROWS 8             // rows per wave in k_adj
#define ECAP 131072        // edge capacity per batch (global)
#define LCAP 24576         // edges cached in LDS by k_cc (96 KB)

// ---------------- K0: pack coords into float4(x,y,z,sq) ---------------------
__global__ void k_prep(const float* __restrict__ coords,
                       float4* __restrict__ pts){
#pragma clang fp contract(off)
  int g = blockIdx.x * blockDim.x + threadIdx.x;   // 8*4096
  float x = coords[g*3+0], y = coords[g*3+1], z = coords[g*3+2];
  // sq: round each square, then sequential adds (XLA mul + reduce, no FMA)
  float sq = ((x*x) + (y*y)) + (z*z);
  pts[g] = make_float4(x, y, z, sq);
}

// ---------------- K1: adjacency bitset + degree/core ------------------------
// one wave handles ROWS=8 rows; word k built with __ballot (j = k*64+lane)
__global__ void k_adj(const float4* __restrict__ pts,
                      unsigned long long* __restrict__ adj,
                      int* __restrict__ core){
#pragma clang fp contract(off)
  int wv   = (blockIdx.x * blockDim.x + threadIdx.x) >> 6;   // 4096 waves
  int lane = threadIdx.x & 63;
  int b  = wv >> 9;                 // 512 waves per batch
  int i0 = (wv & 511) << 3;         // first of 8 rows
  const float4* pb = pts + (b << 12);
  float4 pi[ROWS];
  #pragma unroll
  for (int r = 0; r < ROWS; ++r) pi[r] = pb[i0 + r];
  const float EPS2 = (float)(0.06 * 0.06);
  unsigned long long w[ROWS];
  int deg[ROWS];
  #pragma unroll
  for (int r = 0; r < ROWS; ++r){ w[r] = 0ULL; deg[r] = 0; }
  #pragma unroll 2
  for (int k = 0; k < 64; ++k){
    float4 pj = pb[(k << 6) + lane];
    #pragma unroll
    for (int r = 0; r < ROWS; ++r){
      // dot: ascending-k FMA chain, first product plainly rounded (XLA gebp)
      float dot = __builtin_fmaf(pi[r].z, pj.z,
                  __builtin_fmaf(pi[r].y, pj.y, pi[r].x * pj.x));
      // rn(s - rn(2*dot)) == fma(-2,dot,s) since 2*dot is exact
      float d2 = __builtin_fmaf(-2.0f, dot, pi[r].w + pj.w);
      unsigned long long bal = __ballot(d2 <= EPS2);
      if (lane == k) w[r] = bal;
      deg[r] += __popcll(bal);
    }
  }
  size_t rowg = ((size_t)b << 12) + i0;
  #pragma unroll
  for (int r = 0; r < ROWS; ++r) adj[(rowg + r) * NW + lane] = w[r];
  if (lane == 0){
    #pragma unroll
    for (int r = 0; r < ROWS; ++r) core[rowg + r] = (deg[r] >= 3) ? 1 : 0;
  }
}

// ---------------- K2: core bitset (one wave per batch) ----------------------
__global__ void k_corebits(const int* __restrict__ core,
                           unsigned long long* __restrict__ corebits){
  int b = blockIdx.x;
  int lane = threadIdx.x;   // 64 threads
  unsigned long long myword = 0ULL;
  for (int k = 0; k < 64; ++k){
    unsigned long long bal = __ballot(core[(b << 12) + (k << 6) + lane] != 0);
    if (lane == k) myword = bal;
  }
  corebits[(b << 6) + lane] = myword;
}

// helper: core-core j>i mask for row (wv, lane word)
__device__ __forceinline__ unsigned long long
row_mask(const unsigned long long* __restrict__ adj,
         const unsigned long long* __restrict__ corebits,
         int wv, int b, int i, int lane){
  unsigned long long m = adj[(size_t)wv * NW + lane] & corebits[(b << 6) + lane];
  int base = lane << 6;
  if (base + 63 <= i) m = 0ULL;                       // whole word j <= i
  else if (base <= i) m &= (~0ULL) << (i - base + 1); // keep j > i
  return m;
}

// ---------------- K3a: per-row core-core edge count (no atomics) ------------
__global__ void k_ecnt(const unsigned long long* __restrict__ adj,
                       const unsigned long long* __restrict__ corebits,
                       const int* __restrict__ core,
                       int* __restrict__ rcnt){
  int wv   = (blockIdx.x * blockDim.x + threadIdx.x) >> 6;   // global row
  int lane = threadIdx.x & 63;
  int b = wv >> 12;
  int i = wv & (NPTS - 1);
  int cnt = 0;
  if (core[wv]) cnt = __popcll(row_mask(adj, corebits, wv, b, i, lane));
  #pragma unroll
  for (int off = 32; off; off >>= 1) cnt += __shfl_xor(cnt, off);
  if (lane == 0) rcnt[wv] = cnt;
}

// ---------------- K3b: per-batch exclusive scan of row counts ---------------
__global__ __launch_bounds__(1024) void k_escan(const int* __restrict__ rcnt,
                                                int* __restrict__ roff,
                                                int* __restrict__ ecnt){
  __shared__ int sb[1024];
  int b = blockIdx.x, t = threadIdx.x;
  int v4[4]; int ls = 0;
  for (int s = 0; s < 4; ++s){ v4[s] = rcnt[(b << 12) + (t << 2) + s]; ls += v4[s]; }
  sb[t] = ls;
  __syncthreads();
  for (int off = 1; off < 1024; off <<= 1){
    int x = sb[t];
    int y = (t >= off) ? sb[t - off] : 0;
    __syncthreads();
    sb[t] = x + y;
    __syncthreads();
  }
  int run = (t > 0) ? sb[t - 1] : 0;
  for (int s = 0; s < 4; ++s){ roff[(b << 12) + (t << 2) + s] = run; run += v4[s]; }
  if (t == 1023) ecnt[b] = sb[1023];
}

// ---------------- K3c: fill edges at deterministic offsets ------------------
__global__ void k_efill(const unsigned long long* __restrict__ adj,
                        const unsigned long long* __restrict__ corebits,
                        const int* __restrict__ core,
                        const int* __restrict__ roff,
                        uint32_t* __restrict__ edges){
  int wv   = (blockIdx.x * blockDim.x + threadIdx.x) >> 6;
  int lane = threadIdx.x & 63;
  int b = wv >> 12;
  int i = wv & (NPTS - 1);
  if (!core[wv]) return;                       // wave-uniform exit
  unsigned long long m = row_mask(adj, corebits, wv, b, i, lane);
  int cnt = __popcll(m);
  int incl = cnt;                              // wave inclusive scan
  #pragma unroll
  for (int off = 1; off < 64; off <<= 1){
    int y = __shfl_up(incl, off);
    if (lane >= off) incl += y;
  }
  int pos = roff[wv] + incl - cnt;
  int base = lane << 6;
  uint32_t* eb = edges + (size_t)b * ECAP;
  while (m){
    int bit = __builtin_ctzll(m);
    m &= m - 1;
    if (pos < ECAP) eb[pos] = ((uint32_t)i << 12) | (uint32_t)(base + bit);
    pos++;
  }
}

// ---------------- K4: per-batch connected components, LDS-resident ----------
// lab[i] -> min index of i's core-component; deterministic fixed point
// (atomicMin commutative; exit only after a clean full sweep).
__global__ __launch_bounds__(1024) void k_cc(const uint32_t* __restrict__ edges,
                                             const int* __restrict__ ecnt,
                                             int* __restrict__ lab_g){
  __shared__ int lab[NPTS];
  __shared__ uint32_t ebuf[LCAP];
  __shared__ int chg;
  int b = blockIdx.x, t = threadIdx.x;
  int cnt = min(ecnt[b], ECAP);
  int lcnt = min(cnt, LCAP);
  const uint32_t* eb = edges + (size_t)b * ECAP;
  for (int e = t; e < lcnt; e += 1024) ebuf[e] = eb[e];
  for (int s = 0; s < 4; ++s){ int v = (t << 2) + s; lab[v] = v; }
  __syncthreads();
  while (true){
    if (t == 0) chg = 0;
    __syncthreads();
    for (int e = t; e < cnt; e += 1024){
      uint32_t pk = (e < LCAP) ? ebuf[e] : eb[e];
      int u = pk >> 12, v = pk & 4095;
      int a = lab[u], c = lab[v];
      if (a < c)      { if (atomicMin(&lab[v], a) > a) chg = 1; }
      else if (c < a) { if (atomicMin(&lab[u], c) > c) chg = 1; }
    }
    __syncthreads();
    if (!chg) break;     // clean sweep: nothing lowered -> converged
    // pointer jumping x3 (own-slot writes; racy reads are monotone-safe)
    for (int s = 0; s < 4; ++s){
      int v = (t << 2) + s;
      int l = lab[v];
      l = min(l, lab[l]); l = min(l, lab[l]); l = min(l, lab[l]);
      lab[v] = l;
    }
    __syncthreads();
  }
  for (int s = 0; s < 4; ++s){ int v = (t << 2) + s; lab_g[(b << 12) + v] = lab[v]; }
}

// ---------------- K5: labels (core: lab[i]; border: min core-neighbor lab) --
__global__ void k_labels(const unsigned long long* __restrict__ adj,
                         const unsigned long long* __restrict__ corebits,
                         const int* __restrict__ core,
                         const int* __restrict__ lab_g,
                         int* __restrict__ labels){
  int wv   = (blockIdx.x * blockDim.x + threadIdx.x) >> 6;
  int lane = threadIdx.x & 63;
  int b = wv >> 12;
  int i = wv & (NPTS - 1);
  const int* lb = lab_g + (b << 12);
  unsigned long long m = adj[(size_t)wv * NW + lane] & corebits[(b << 6) + lane];
  int mn = SENT;
  int base = lane << 6;
  while (m){
    int bit = __builtin_ctzll(m);
    m &= m - 1;
    mn = min(mn, lb[base + bit]);
  }
  #pragma unroll
  for (int off = 32; off; off >>= 1) mn = min(mn, __shfl_xor(mn, off));
  if (lane == 0){
    labels[wv] = core[wv] ? lb[i] : mn;   // SENT if no core neighbor
  }
}

// ---------------- K6: per-batch finalize (noise fill, compact, cap) ---------
__global__ __launch_bounds__(1024) void k_final(const int* __restrict__ labels_g,
                                                int* __restrict__ out){
  __shared__ int LAB[NPTS];
  __shared__ int A[NPTS];
  __shared__ int B[NPTS];
  __shared__ int scanbuf[1024];
  __shared__ int sMost;
  int b = blockIdx.x;
  int t = threadIdx.x;
  const int* lg = labels_g + (b << 12);

  for (int s = 0; s < 4; ++s){ int v = (t << 2) + s; LAB[v] = lg[v]; A[v] = 0; }
  if (t == 0) sMost = -1;
  __syncthreads();
  for (int s = 0; s < 4; ++s){ int l = LAB[(t << 2) + s]; if (l < SENT) atomicAdd(&A[l], 1); }
  __syncthreads();
  for (int s = 0; s < 4; ++s){
    int v = (t << 2) + s; int c = A[v];
    if (c > 0) atomicMax(&sMost, (c << 13) | (4095 - v));
  }
  __syncthreads();
  int most = (sMost >= 0) ? (4095 - (sMost & 8191)) : 0;
  for (int s = 0; s < 4; ++s){ int v = (t << 2) + s; if (LAB[v] == SENT) LAB[v] = most; B[v] = 0; }
  __syncthreads();
  for (int s = 0; s < 4; ++s) B[LAB[(t << 2) + s]] = 1;
  __syncthreads();
  int pv[4]; int ls = 0;
  for (int s = 0; s < 4; ++s){ pv[s] = B[(t << 2) + s]; ls += pv[s]; }
  scanbuf[t] = ls;
  __syncthreads();
  for (int off = 1; off < 1024; off <<= 1){
    int x = scanbuf[t];
    int y = (t >= off) ? scanbuf[t - off] : 0;
    __syncthreads();
    scanbuf[t] = x + y;
    __syncthreads();
  }
  int ncl = scanbuf[1023];
  int run = (t > 0) ? scanbuf[t - 1] : 0;
  for (int s = 0; s < 4; ++s){ run += pv[s]; B[(t << 2) + s] = run - 1; }
  __syncthreads();
  for (int s = 0; s < 4; ++s){ int v = (t << 2) + s; LAB[v] = B[LAB[v]]; }
  __syncthreads();
  if (ncl > MAXSP){
    for (int s = 0; s < 4; ++s) A[(t << 2) + s] = 0;
    __syncthreads();
    for (int s = 0; s < 4; ++s) atomicAdd(&A[LAB[(t << 2) + s]], 1);
    __syncthreads();
    for (int s = 0; s < 4; ++s){
      int v = (t << 2) + s;
      int keyv = A[v] * NPTS + v;
      int pos = 0;
      for (int u = 0; u < NPTS; ++u) pos += ((A[u] * NPTS + u) < keyv) ? 1 : 0;
      B[v] = (pos >= NPTS - MAXSP) ? (pos - (NPTS - MAXSP)) : 0;
    }
    __syncthreads();
    for (int s = 0; s < 4; ++s){ int v = (t << 2) + s; LAB[v] = B[LAB[v]]; }
    __syncthreads();
  }
  int* og = out + (b << 12);
  for (int s = 0; s < 4; ++s){ int v = (t << 2) + s; og[v] = LAB[v]; }
}

// ---------------- launch ----------------------------------------------------
extern "C" void kernel_launch(void* const* d_in, const int* in_sizes, int n_in,
                              void* d_out, int out_size, void* d_ws, size_t ws_size,
                              hipStream_t stream){
  const float* coords = (const float*)d_in[0];
  int* out = (int*)d_out;
  int batches = in_sizes[0] / (NPTS * 3);   // 8

  char* ws = (char*)d_ws;
  unsigned long long* adj = (unsigned long long*)ws;                  // 16 MB
  size_t off = (size_t)batches * NPTS * NW * sizeof(unsigned long long);
  int* core   = (int*)(ws + off); off += (size_t)batches * NPTS * sizeof(int);
  unsigned long long* corebits = (unsigned long long*)(ws + off);
  off += (size_t)batches * 64 * sizeof(unsigned long long);
  int* lab_g  = (int*)(ws + off); off += (size_t)batches * NPTS * sizeof(int);
  int* labels = (int*)(ws + off); off += (size_t)batches * NPTS * sizeof(int);
  float4* pts = (float4*)(ws + off); off += (size_t)batches * NPTS * sizeof(float4);
  int* rcnt   = (int*)(ws + off); off += (size_t)batches * NPTS * sizeof(int);
  int* roff   = (int*)(ws + off); off += (size_t)batches * NPTS * sizeof(int);
  int* ecnt   = (int*)(ws + off); off += 256;
  uint32_t* edges = (uint32_t*)(ws + off); off += (size_t)batches * ECAP * sizeof(uint32_t);

  int npts_all = batches * NPTS;
  // K0: pack float4(x,y,z,sq)
  k_prep<<<npts_all / 256, 256, 0, stream>>>(coords, pts);
  // K1: adjacency, 8 rows per wave
  k_adj<<<npts_all / (ROWS * 4), 256, 0, stream>>>(pts, adj, core);
  // K2: core bitset
  k_corebits<<<batches, 64, 0, stream>>>(core, corebits);
  // K3a: per-row edge counts (no atomics)
  k_ecnt<<<npts_all / 4, 256, 0, stream>>>(adj, corebits, core, rcnt);
  // K3b: per-batch scan -> deterministic offsets
  k_escan<<<batches, 1024, 0, stream>>>(rcnt, roff, ecnt);
  // K3c: fill edges
  k_efill<<<npts_all / 4, 256, 0, stream>>>(adj, corebits, core, roff, edges);
  // K4: per-batch CC, LDS-resident edges
  k_cc<<<batches, 1024, 0, stream>>>(edges, ecnt, lab_g);
  // K5: label extraction
  k_labels<<<npts_all / 4, 256, 0, stream>>>(adj, corebits, core, lab_g, labels);
  // K6: per-batch finalize
  k_final<<<batches, 1024, 0, stream>>>(labels, out);
}